// Round 6
// baseline (33063.879 us; speedup 1.0000x reference)
//
#include <hip/hip_runtime.h>
#include <hip/hip_fp16.h>

#define EPSF 1e-8f
#define SCOPE_AGT __HIP_MEMORY_SCOPE_AGENT

// T=512 B=64 IN=256 OUT=256 H=512 N=2048 C=64 R=4
// 256 blocks x 1024 threads (cooperative, 1/CU). Dual-role blocks:
//  GEMM role: block q computes gates for 8 cols x all 64 batches from a 12KB
//             LDS-resident weight slice (weights read ONCE per step chip-wide,
//             was 218 MB/step of redundant L2 streams).
//  batch role: block (b,chunk) owns 512 mem slots in registers, does r-GEMV
//             (LDS-resident Wr), LSTM, fp16 local projections, mem pass.
// Barriers: G (gates), H (h) global monotone counters (8 per-XCD lines);
// ACC per-batch. gbuf parity double-buffered; h/gates/Acc races excluded by
// barrier ordering (producer's next overwrite gated behind consumer's post).

typedef _Float16 h2_t __attribute__((ext_vector_type(2)));

struct P6 {
  const unsigned* W3;    // [256 q][384 rp][8 c] u32 = half2{row 2rp,2rp+1}
  const _Float16* Wr;    // [4 chunk][64 c][512 k]
  const _Float16* Wp;    // [512 row][384 cl]  cl: key64|gen64|y256
  const float* b_lstm;   // 2048
  const float* b_out;    // 256
  const float* b_key;    // 64
  const float* W_beta;   // 512
  const float* b_beta;   // 1
  const float* b_gen;    // 64
  const unsigned* xP;    // [512 t][128 rp][64 b] u32 = half2{x 2rp,2rp+1}
  unsigned* hP;          // [256 rp][64 b] u32 = half2{h 2rp,2rp+1}
  float* gbuf;           // [2 par][64 b][2048 k]
  float* AccP;           // [64 b][4 chunk][64 c]
  float* ZP;             // [64 b][4]
  float* S2P;            // [64 b][4]
  unsigned* ctr;         // [64 b][32]
  unsigned* gctr;        // [512]: G at x*32 (x=0..7), H at 256+x*32
  float* out;            // [512][64][256] + loss at 8388608
};

__device__ __forceinline__ float sigm(float x) { return 1.f / (1.f + __expf(-x)); }
__device__ __forceinline__ float aload(const float* p) {
  return __hip_atomic_load(p, __ATOMIC_RELAXED, SCOPE_AGT);
}
__device__ __forceinline__ void astore(float* p, float v) {
  __hip_atomic_store(p, v, __ATOMIC_RELAXED, SCOPE_AGT);
}
__device__ __forceinline__ unsigned aload_u(const unsigned* p) {
  return __hip_atomic_load(p, __ATOMIC_RELAXED, SCOPE_AGT);
}
__device__ __forceinline__ void astore_u(unsigned* p, unsigned v) {
  __hip_atomic_store(p, v, __ATOMIC_RELAXED, SCOPE_AGT);
}
__device__ __forceinline__ h2_t u2h(unsigned u) {
  union { unsigned u; h2_t h; } x; x.u = u; return x.h;
}
__device__ __forceinline__ unsigned h2u(h2_t h) {
  union { h2_t h; unsigned u; } x; x.h = h; return x.u;
}

#if defined(__has_builtin)
#if __has_builtin(__builtin_amdgcn_fdot2)
#define HAVE_FDOT2 1
#endif
#endif

__device__ __forceinline__ float dot2acc(h2_t a, h2_t b, float c) {
#ifdef HAVE_FDOT2
  return __builtin_amdgcn_fdot2(a, b, c, false);
#else
  return fmaf((float)a.x, (float)b.x, fmaf((float)a.y, (float)b.y, c));
#endif
}

__global__ void __launch_bounds__(1024, 4) dnc_b6(P6 P) {
  const int tid   = threadIdx.x;
  const int bid   = blockIdx.x;
  const int chunk = bid & 3;            // batch role (XCD-constant: bid%8 fixes bid&3)
  const int b     = bid >> 2;
  const int qck   = bid >> 6;           // GEMM role col decode
  const int qm    = bid & 63;
  const int lane  = tid & 63;
  const int wv    = tid >> 6;           // 0..15
  const int sgrp  = lane >> 4;
  const int c4    = lane & 15;
  const int xcd   = bid & 7;

  __shared__ unsigned  s_w3[3072];      // 12KB GEMM slice (pair-packed)
  __shared__ _Float16  s_wr[32768];     // 64KB r-row weights for own chunk
  __shared__ float s_part[8192];        // 32KB scratch
  __shared__ float s_h[512];
  __shared__ float s_gt[512];
  __shared__ float s_e[512];
  __shared__ float s_rr[64];
  __shared__ float s_c[128];
  __shared__ float s_key[64], s_kprev[64], s_genv[64];
  __shared__ float s_wred[32];
  __shared__ float s_scal[4];           // 0:invZ_prev 1:S2_prev 2:beta 3:||key||

  float4 mreg[8];
  float  sden[8];
#pragma unroll
  for (int i = 0; i < 8; ++i) mreg[i] = make_float4(0.f, 0.f, 0.f, 0.f);

  // stage weight slices (persist across all 512 steps)
  for (int i = tid; i < 3072; i += 1024) s_w3[i] = P.W3[(size_t)bid * 3072 + i];
  {
    const unsigned* wr32 = (const unsigned*)(P.Wr + (size_t)chunk * 32768);
    unsigned* swr32 = (unsigned*)s_wr;
    for (int i = tid; i < 16384; i += 1024) swr32[i] = wr32[i];
  }
  if (tid < 512) s_e[tid] = 0.f;
  if (tid < 128) s_c[tid] = 0.f;
  if (tid < 64) { s_kprev[tid] = 0.f; s_rr[tid] = 0.f; }
  if (tid == 0) { s_scal[0] = 0.f; s_scal[1] = 0.f; s_scal[2] = 0.f; s_scal[3] = 0.f; }
  float lossacc = 0.f;
  __syncthreads();

  for (int t = 0; t < 512; ++t) {
    const int par = t & 1;

    //===== A1: GEMM slice — gates[64 b][8 own cols] from x_t + h_{t-1} =====
    {
      const unsigned* xrow = P.xP + (size_t)t * 8192;
      float a8[8] = {0.f, 0.f, 0.f, 0.f, 0.f, 0.f, 0.f, 0.f};
      const int lo = wv * 24;
#pragma unroll 8
      for (int i = 0; i < 24; ++i) {
        const int rp = lo + i;
        unsigned uv;
        if (rp < 128) uv = xrow[rp * 64 + lane];
        else          uv = aload_u(P.hP + (rp - 128) * 64 + lane);
        const h2_t vv = u2h(uv);
        const unsigned* w8 = &s_w3[rp * 8];
#pragma unroll
        for (int c = 0; c < 8; ++c) a8[c] = dot2acc(u2h(w8[c]), vv, a8[c]);
      }
#pragma unroll
      for (int c = 0; c < 8; ++c) s_part[(wv * 64 + lane) * 8 + c] = a8[c];
    }
    __syncthreads();
    if (tid < 512) {
      const int b2 = tid >> 3, c = tid & 7;
      float v = 0.f;
#pragma unroll
      for (int k = 0; k < 16; ++k) v += s_part[(k * 64 + b2) * 8 + c];
      astore(P.gbuf + par * 131072 + b2 * 2048 + qck * 512 + qm * 8 + c, v);
    }
    __syncthreads();                                  // drains gbuf stores
    if (tid == 0)
      __hip_atomic_fetch_add(P.gctr + xcd * 32, 1u, __ATOMIC_RELEASE, SCOPE_AGT);  // post G

    //===== A2: per-batch wait ACC_{t-1}; finalize r_{t-1} =====
    if (t > 0) {
      if (tid == 0) {
        while (__hip_atomic_load(P.ctr + b * 32, __ATOMIC_RELAXED, SCOPE_AGT) < 4u * (unsigned)t)
          __builtin_amdgcn_s_sleep(1);
      }
      __syncthreads();
      float a0 = 0.f, a1 = 0.f, a2 = 0.f, a3 = 0.f;
      if (tid < 64) {
        const float* ap = P.AccP + b * 256 + tid;
        a0 = aload(ap); a1 = aload(ap + 64); a2 = aload(ap + 128); a3 = aload(ap + 192);
      } else if (tid == 64) {
        const float* zp = P.ZP + b * 4;
        const float* sp = P.S2P + b * 4;
        const float Z  = aload(zp) + aload(zp + 1) + aload(zp + 2) + aload(zp + 3);
        const float S2 = aload(sp) + aload(sp + 1) + aload(sp + 2) + aload(sp + 3);
        s_scal[0] = 1.f / Z;  s_scal[1] = S2;
      }
      __syncthreads();
      if (tid < 64) {
        const float iZ = s_scal[0];
        s_rr[tid] = iZ * (a0 + a1 + a2 + a3) + s_scal[1] * iZ * iZ * s_kprev[tid];
      }
      __syncthreads();
    }

    //===== A3: wait G; assemble own 512 gate cols + r-part =====
    if (tid == 0) {
      const unsigned tgt = 256u * (unsigned)(t + 1);
      for (;;) {
        unsigned s = 0;
#pragma unroll
        for (int x = 0; x < 8; ++x) s += __hip_atomic_load(P.gctr + x * 32, __ATOMIC_RELAXED, SCOPE_AGT);
        if (s >= tgt) break;
        __builtin_amdgcn_s_sleep(1);
      }
    }
    __syncthreads();
    {
      float gval = 0.f;
      if (tid < 512) gval = aload(P.gbuf + par * 131072 + b * 2048 + chunk * 512 + tid);
      const int k = tid & 511, half = tid >> 9;
      const _Float16* wc = s_wr + half * (32 * 512) + k;
      const float* rr = s_rr + half * 32;
      float a = 0.f;
#pragma unroll 8
      for (int cI = 0; cI < 32; ++cI) a = fmaf((float)wc[cI * 512], rr[cI], a);
      s_part[half * 512 + k] = a;
      if (tid < 512) s_gt[tid] = gval;
    }
    __syncthreads();

    //===== A4: LSTM -> h_t (own 128 j), publish hP pairs =====
    if (tid < 128) {
      const int jl = tid;
      const int kb = (jl >> 1) * 8 + (jl & 1) * 4;
      const float gi = s_gt[kb]     + s_part[kb]     + s_part[512 + kb]     + P.b_lstm[chunk * 128 + jl];
      const float gf = s_gt[kb + 1] + s_part[kb + 1] + s_part[512 + kb + 1] + P.b_lstm[512 + chunk * 128 + jl];
      const float gg = s_gt[kb + 2] + s_part[kb + 2] + s_part[512 + kb + 2] + P.b_lstm[1024 + chunk * 128 + jl];
      const float go = s_gt[kb + 3] + s_part[kb + 3] + s_part[512 + kb + 3] + P.b_lstm[1536 + chunk * 128 + jl];
      const float cn = sigm(gf) * s_c[jl] + sigm(gi) * tanhf(gg);
      s_c[jl] = cn;
      s_h[chunk * 128 + jl] = sigm(go) * tanhf(cn);
    }
    __syncthreads();
    if (tid < 64) {
      h2_t hh;
      hh.x = (_Float16)s_h[chunk * 128 + 2 * tid];
      hh.y = (_Float16)s_h[chunk * 128 + 2 * tid + 1];
      astore_u(P.hP + (chunk * 64 + tid) * 64 + b, h2u(hh));
    }
    __syncthreads();                                  // drains hP stores
    if (tid == 0)
      __hip_atomic_fetch_add(P.gctr + 256 + xcd * 32, 1u, __ATOMIC_RELEASE, SCOPE_AGT);  // post H

    //===== A5 (H-barrier shadow): apply pending rank-1 update; slot norms =====
    {
      const float invZp = s_scal[0];
      const float4 kp4 = ((const float4*)s_kprev)[c4];
      const int nbase = (wv * 4 + sgrp) * 8;
#pragma unroll
      for (int it = 0; it < 8; ++it) {
        float4 m4 = mreg[it];
        const float wpv = s_e[nbase + it] * invZp;    // w_{t-1}[n] (0 at t=0)
        m4.x = fmaf(wpv, kp4.x, m4.x); m4.y = fmaf(wpv, kp4.y, m4.y);
        m4.z = fmaf(wpv, kp4.z, m4.z); m4.w = fmaf(wpv, kp4.w, m4.w);
        float ssq = m4.x * m4.x + m4.y * m4.y + m4.z * m4.z + m4.w * m4.w;
#pragma unroll
        for (int off = 1; off < 16; off <<= 1) ssq += __shfl_xor(ssq, off);
        sden[it] = fmaxf(sqrtf(ssq), EPSF);
        mreg[it] = m4;
      }
    }

    //===== A6: wait H; read full h_t =====
    if (tid == 0) {
      const unsigned tgt = 256u * (unsigned)(t + 1);
      for (;;) {
        unsigned s = 0;
#pragma unroll
        for (int x = 0; x < 8; ++x) s += __hip_atomic_load(P.gctr + 256 + x * 32, __ATOMIC_RELAXED, SCOPE_AGT);
        if (s >= tgt) break;
        __builtin_amdgcn_s_sleep(1);
      }
    }
    __syncthreads();
    if (tid < 256) {
      const h2_t hh = u2h(aload_u(P.hP + tid * 64 + b));
      s_h[2 * tid]     = (float)hh.x;
      s_h[2 * tid + 1] = (float)hh.y;
    }
    __syncthreads();

    //===== A7: local projections (fp16) + beta/||key||/loss + y out =====
    {
      {  // key|gen: 8 rowgroups x 128 cols
        const int rg = tid >> 7, cl = tid & 127;
        const _Float16* wp = P.Wp + cl;
        const float* hh = s_h + rg * 64;
        float a = 0.f;
#pragma unroll 8
        for (int r = 0; r < 64; ++r) a = fmaf(hh[r], (float)wp[(size_t)(rg * 64 + r) * 384], a);
        s_part[rg * 128 + cl] = a;
      }
      {  // y own 64-col slice: 16 rowgroups x 64 cols
        const int rg = tid >> 6, c6 = tid & 63;
        const _Float16* wp = P.Wp + 128 + chunk * 64 + c6;
        const float* hh = s_h + rg * 32;
        float a = 0.f;
#pragma unroll 8
        for (int r = 0; r < 32; ++r) a = fmaf(hh[r], (float)wp[(size_t)(rg * 32 + r) * 384], a);
        s_part[1024 + rg * 64 + c6] = a;
      }
      {  // beta partials
        float pb = (tid < 512) ? s_h[tid] * P.W_beta[tid] : 0.f;
#pragma unroll
        for (int off = 32; off; off >>= 1) pb += __shfl_down(pb, off);
        if (tid < 512 && lane == 0) s_wred[wv] = pb;
      }
    }
    __syncthreads();
    if (tid < 64) {
      float v = 0.f;
#pragma unroll
      for (int k = 0; k < 8; ++k) v += s_part[k * 128 + tid];
      s_key[tid] = v + P.b_key[tid];
    } else if (tid < 128) {
      const int c = tid - 64;
      float v = 0.f;
#pragma unroll
      for (int k = 0; k < 8; ++k) v += s_part[k * 128 + 64 + c];
      s_genv[c] = v + P.b_gen[c];
    } else if (tid < 192) {
      const int col = tid - 128, oc = chunk * 64 + col;
      float v = 0.f;
#pragma unroll
      for (int k = 0; k < 16; ++k) v += s_part[1024 + k * 64 + col];
      P.out[((size_t)t * 64 + b) * 256 + oc] = v + P.b_out[oc];
    } else if (tid == 192) {
      float s = P.b_beta[0];
#pragma unroll
      for (int k = 0; k < 8; ++k) s += s_wred[k];
      s_scal[2] = (s > 20.f) ? s : log1pf(__expf(s));   // softplus
    }
    __syncthreads();
    if (wv == 0) {
      const float kv = s_key[lane];
      float sq = kv * kv;
#pragma unroll
      for (int off = 32; off; off >>= 1) sq += __shfl_down(sq, off);
      if (lane == 0) s_scal[3] = fmaxf(sqrtf(sq), EPSF);
    } else if (wv == 1 && chunk == 0) {
      const float d = s_key[lane] - s_genv[lane];
      float ds = d * d;
#pragma unroll
      for (int off = 32; off; off >>= 1) ds += __shfl_down(ds, off);
      if (lane == 0) lossacc += ds;                      // tid 64
    }
    __syncthreads();

    //===== A8: sim/exp/acc on register mem; publish Acc/Z/S2; post ACC =====
    {
      const float beta = s_scal[2], kn = s_scal[3];
      const float4 kk = ((const float4*)s_key)[c4];
      float Zp = 0.f, S2p = 0.f;
      float4 acc4 = make_float4(0.f, 0.f, 0.f, 0.f);
      const int nbase = (wv * 4 + sgrp) * 8;
#pragma unroll
      for (int it = 0; it < 8; ++it) {
        const float4 m4 = mreg[it];
        float num = m4.x * kk.x + m4.y * kk.y + m4.z * kk.z + m4.w * kk.w;
#pragma unroll
        for (int off = 1; off < 16; off <<= 1) num += __shfl_xor(num, off);
        const float e = __expf(beta * (num / (sden[it] * kn)));
        if (c4 == 0) { s_e[nbase + it] = e; Zp += e; S2p += e * e; }
        acc4.x = fmaf(e, m4.x, acc4.x); acc4.y = fmaf(e, m4.y, acc4.y);
        acc4.z = fmaf(e, m4.z, acc4.z); acc4.w = fmaf(e, m4.w, acc4.w);
      }
#pragma unroll
      for (int off = 32; off; off >>= 1) { Zp += __shfl_down(Zp, off); S2p += __shfl_down(S2p, off); }
      if (lane == 0) { s_wred[wv] = Zp; s_wred[16 + wv] = S2p; }
#pragma unroll
      for (int off = 16; off < 64; off <<= 1) {
        acc4.x += __shfl_down(acc4.x, off); acc4.y += __shfl_down(acc4.y, off);
        acc4.z += __shfl_down(acc4.z, off); acc4.w += __shfl_down(acc4.w, off);
      }
      if (lane < 16) ((float4*)s_part)[wv * 16 + lane] = acc4;
    }
    __syncthreads();
    if (tid < 64) {
      float a = 0.f;
#pragma unroll
      for (int w = 0; w < 16; ++w) a += s_part[w * 64 + tid];
      astore(P.AccP + (b * 4 + chunk) * 64 + tid, a);
      s_kprev[tid] = s_key[tid];
    } else if (tid == 64) {
      float Z = 0.f, S2 = 0.f;
#pragma unroll
      for (int k = 0; k < 16; ++k) { Z += s_wred[k]; S2 += s_wred[16 + k]; }
      astore(P.ZP + b * 4 + chunk, Z);
      astore(P.S2P + b * 4 + chunk, S2);
    }
    __syncthreads();                                  // drains stores
    if (tid == 0)
      __hip_atomic_fetch_add(P.ctr + b * 32, 1u, __ATOMIC_RELEASE, SCOPE_AGT);  // post ACC
  }

  if (chunk == 0 && tid == 64) atomicAdd(P.out + 8388608, lossacc * (1.f / 4096.f));
}

//============================ prep kernels ============================
// W3[q][rp][c]: q=(qck<<6)|qm covers orig col (c&3)*512 + qck*128 + 2*qm + (c>>2);
// rows [0,256)=W_ih(x), [256,768)=W_hh; pair-packed over (2rp,2rp+1).
__global__ void build_w3(const float* __restrict__ W_ih, const float* __restrict__ W_hh,
                         unsigned* __restrict__ W3) {
  const int id = blockIdx.x * 256 + threadIdx.x;      // 786432
  if (id >= 786432) return;
  const int q = id / 3072, rem = id % 3072;
  const int rp = rem >> 3, c = rem & 7;
  const int col = (c & 3) * 512 + (q >> 6) * 128 + (q & 63) * 2 + (c >> 2);
  float v[2];
#pragma unroll
  for (int k = 0; k < 2; ++k) {
    const int row = 2 * rp + k;
    v[k] = (row < 256) ? W_ih[(size_t)row * 2048 + col]
                       : W_hh[(size_t)(row - 256) * 2048 + col];
  }
  h2_t h; h.x = (_Float16)v[0]; h.y = (_Float16)v[1];
  W3[id] = h2u(h);
}

// Wr[chunk][cc][k]: R=4-head-folded read rows; k=(jl>>1)*8+(jl&1)*4+g.
__global__ void build_wr(const float* __restrict__ W_ih, _Float16* __restrict__ Wr) {
  const int id = blockIdx.x * 256 + threadIdx.x;      // 131072
  if (id >= 131072) return;
  const int chunk = id >> 15, rem = id & 32767;
  const int cc = rem >> 9, k = rem & 511;
  const int jl = (k >> 3) * 2 + ((k >> 2) & 1), g = k & 3;
  const int col = g * 512 + chunk * 128 + jl;
  const float* p0 = W_ih + (size_t)(256 + cc * 4) * 2048 + col;
  Wr[id] = (_Float16)(p0[0] + p0[2048] + p0[4096] + p0[6144]);
}

// Wp[row][cl]: cl<64 key, <128 gen, else y (W_out).
__global__ void build_wp(const float* __restrict__ W_key, const float* __restrict__ W_gen,
                         const float* __restrict__ W_out, _Float16* __restrict__ Wp) {
  const int id = blockIdx.x * 256 + threadIdx.x;      // 196608
  if (id >= 196608) return;
  const int row = id / 384, cl = id % 384;
  float v;
  if (cl < 64)       v = W_key[(size_t)row * 64 + cl];
  else if (cl < 128) v = W_gen[(size_t)row * 64 + cl - 64];
  else               v = W_out[(size_t)row * 256 + cl - 128];
  Wp[id] = (_Float16)v;
}

// xP[t][rp][b] = half2{xs[t][b][2rp], xs[t][b][2rp+1]}
__global__ void build_xp(const float* __restrict__ xs, unsigned* __restrict__ xP) {
  const int id = blockIdx.x * 256 + threadIdx.x;      // 4194304
  if (id >= 4194304) return;
  const int t = id >> 13, rem = id & 8191;
  const int rp = rem >> 6, bb = rem & 63;
  const float* p = xs + ((size_t)t * 64 + bb) * 256 + 2 * rp;
  h2_t h; h.x = (_Float16)p[0]; h.y = (_Float16)p[1];
  xP[id] = h2u(h);
}

extern "C" void kernel_launch(void* const* d_in, const int* in_sizes, int n_in,
                              void* d_out, int out_size, void* d_ws, size_t ws_size,
                              hipStream_t stream) {
  const float* xs     = (const float*)d_in[0];
  const float* W_ih   = (const float*)d_in[1];
  const float* W_hh   = (const float*)d_in[2];
  const float* b_lstm = (const float*)d_in[3];
  const float* W_out  = (const float*)d_in[4];
  const float* b_out  = (const float*)d_in[5];
  const float* W_key  = (const float*)d_in[6];
  const float* b_key  = (const float*)d_in[7];
  const float* W_beta = (const float*)d_in[8];
  const float* b_beta = (const float*)d_in[9];
  const float* W_gen  = (const float*)d_in[10];
  const float* b_gen  = (const float*)d_in[11];
  float* out = (float*)d_out;

  float* ws = (float*)d_ws;
  unsigned*  W3  = (unsigned*)ws;               // 786,432 u32
  _Float16*  Wr  = (_Float16*)(ws + 786432);    // 131,072 h (65,536 f)
  _Float16*  Wp  = (_Float16*)(ws + 851968);    // 196,608 h (98,304 f)
  unsigned*  xP  = (unsigned*)(ws + 950272);    // 4,194,304 u32
  unsigned*  hP  = (unsigned*)(ws + 5144576);   // 16,384 u32
  float*     gbuf = ws + 5160960;               // 262,144 f
  float*     AccP = ws + 5423104;               // 16,384 f
  float*     ZP   = ws + 5439488;               // 256 f
  float*     S2P  = ws + 5439744;               // 256 f
  unsigned*  ctr  = (unsigned*)(ws + 5440000);  // 2,048 u32
  unsigned*  gctr = (unsigned*)(ws + 5442048);  // 512 u32

  hipMemsetAsync(hP, 0, 16384 * sizeof(unsigned), stream);          // h_{-1} = 0
  hipMemsetAsync(ctr, 0, (2048 + 512) * sizeof(unsigned), stream);  // ctr + gctr
  hipMemsetAsync(out + 8388608, 0, sizeof(float), stream);          // loss

  build_w3<<<dim3(3072),  dim3(256), 0, stream>>>(W_ih, W_hh, W3);
  build_wr<<<dim3(512),   dim3(256), 0, stream>>>(W_ih, Wr);
  build_wp<<<dim3(768),   dim3(256), 0, stream>>>(W_key, W_gen, W_out, Wp);
  build_xp<<<dim3(16384), dim3(256), 0, stream>>>(xs, xP);

  P6 prm;
  prm.W3 = W3; prm.Wr = Wr; prm.Wp = Wp;
  prm.b_lstm = b_lstm; prm.b_out = b_out; prm.b_key = b_key;
  prm.W_beta = W_beta; prm.b_beta = b_beta; prm.b_gen = b_gen;
  prm.xP = xP; prm.hP = hP; prm.gbuf = gbuf;
  prm.AccP = AccP; prm.ZP = ZP; prm.S2P = S2P;
  prm.ctr = ctr; prm.gctr = gctr; prm.out = out;

  void* kargs[] = { &prm };
  hipLaunchCooperativeKernel(reinterpret_cast<void*>(&dnc_b6),
                             dim3(256), dim3(1024), kargs, 0, stream);
}

// Round 8
// 19663.907 us; speedup vs baseline: 1.6815x; 1.6815x over previous
//
#include <hip/hip_runtime.h>
#include <hip/hip_fp16.h>

#define EPSF 1e-8f
#define SCOPE_AGT __HIP_MEMORY_SCOPE_AGENT

// T=512 B=64 IN=256 OUT=256 H=512 N=2048 C=64 R=4
// 512 blocks x 512 threads, PLAIN launch. Co-residency forced by LDS sizing:
// ~15KB static + 40KB dummy dynamic = ~55KB -> exactly 2 blocks/CU ->
// all 512 blocks resident (512 = 2 x 256 CUs), so monotone-counter barriers
// are deadlock-free without hipLaunchCooperativeKernel (round-7 failure mode).
// 8 blocks per batch: per-block W2h slice 426KB (half of round 5) -> shorter
// per-chain weight stream; 2 independent batch-chains per CU overlap stalls.

typedef _Float16 h2_t __attribute__((ext_vector_type(2)));

struct P8 {
  const unsigned* W2h;  // [8 chunk][416 rp][256 cc] u32 = half2{row 2rp,2rp+1}
  const _Float16* Wkg;  // [512 row][128 cl]  cl: key64|gen64
  const _Float16* Wy;   // [512 row][256 col]
  const float* b_lstm;  // 2048
  const float* b_out;   // 256
  const float* b_key;   // 64
  const float* W_beta;  // 512
  const float* b_beta;  // 1
  const float* b_gen;   // 64
  const float* xs;      // [512][64][256]
  float* hbuf;          // [64 b][512]
  float* AccP;          // [64 b][8 chunk][64 c]
  float* ZP;            // [64 b][8]
  float* S2P;           // [64 b][8]
  unsigned* ctr;        // [64 b][16]
  float* out;           // [512][64][256] + loss at 8388608
};

__device__ __forceinline__ float sigm(float x) { return 1.f / (1.f + __expf(-x)); }
__device__ __forceinline__ float aload(const float* p) {
  return __hip_atomic_load(p, __ATOMIC_RELAXED, SCOPE_AGT);
}
__device__ __forceinline__ void astore(float* p, float v) {
  __hip_atomic_store(p, v, __ATOMIC_RELAXED, SCOPE_AGT);
}
__device__ __forceinline__ h2_t u2h(unsigned u) {
  union { unsigned u; h2_t h; } x; x.u = u; return x.h;
}

#if defined(__has_builtin)
#if __has_builtin(__builtin_amdgcn_fdot2)
#define HAVE_FDOT2 1
#endif
#endif

__device__ __forceinline__ float dot2acc(h2_t a, h2_t b, float c) {
#ifdef HAVE_FDOT2
  return __builtin_amdgcn_fdot2(a, b, c, false);
#else
  return fmaf((float)a.x, (float)b.x, fmaf((float)a.y, (float)b.y, c));
#endif
}

__global__ void __launch_bounds__(512, 4) dnc_b8(P8 P) {
  const int tid   = threadIdx.x;
  const int bid   = blockIdx.x;
  const int chunk = bid & 7;            // XCD-constant under bid%8 round-robin
  const int b     = bid >> 3;
  const int lane  = tid & 63;
  const int wv    = tid >> 6;           // 0..7
  const int sgrp  = lane >> 4;
  const int c4    = lane & 15;

  __shared__ _Float16 s_ih[832];        // fp16 GEMV input [x(256)|h(512)|r(64)]
  __shared__ float s_h[512];            // fp32 h (projections)
  __shared__ float s_gates[256];
  __shared__ float s_c[64];
  __shared__ float s_part[2048];
  __shared__ float s_e[256];
  __shared__ float s_key[64], s_kprev[64], s_genv[64];
  __shared__ float s_wred[32];
  __shared__ float s_bred[8];
  __shared__ float s_scal[4];           // 0:invZ_prev 1:S2_prev 2:beta 3:||key||

  unsigned* ctr = P.ctr + b * 16;

  float4 mreg[8];                       // own 256 mem slots
  float  sden[8];
#pragma unroll
  for (int i = 0; i < 8; ++i) mreg[i] = make_float4(0.f, 0.f, 0.f, 0.f);

  // init LDS state; load x_0
  for (int i = 256 + tid; i < 832; i += 512) s_ih[i] = (_Float16)0.f;
  if (tid < 512) s_h[tid] = 0.f;
  if (tid < 256) s_e[tid] = 0.f;
  if (tid < 64) { s_c[tid] = 0.f; s_kprev[tid] = 0.f; }
  if (tid < 128) {
    const float2 xv = ((const float2*)P.xs)[(size_t)b * 128 + tid];
    h2_t hv; hv.x = (_Float16)xv.x; hv.y = (_Float16)xv.y;
    *(h2_t*)&s_ih[tid * 2] = hv;
  }
  if (tid == 0) { s_scal[0] = 0.f; s_scal[1] = 0.f; }
  float lossacc = 0.f;
  __syncthreads();

  const int q  = tid >> 6;              // 0..7 rowpair-group (wave-uniform)
  const int cg = tid & 63;              // col-group (4 cols)
  const unsigned* wbase = P.W2h + (size_t)chunk * 106496 + (cg << 2);

  for (int t = 0; t < 512; ++t) {
    // ---- GEMV part 1: rowpairs [q*48,+48) (x+h rows)
    float4 acc = make_float4(0.f, 0.f, 0.f, 0.f);
    {
      const unsigned* wp = wbase + (size_t)(q * 48) * 256;
      const _Float16* ip = s_ih + q * 96;
#pragma unroll 4
      for (int r = 0; r < 48; ++r) {
        const uint4 w = *(const uint4*)(wp + (size_t)r * 256);
        const h2_t v = *(const h2_t*)(ip + r * 2);
        acc.x = dot2acc(u2h(w.x), v, acc.x);
        acc.y = dot2acc(u2h(w.y), v, acc.y);
        acc.z = dot2acc(u2h(w.z), v, acc.z);
        acc.w = dot2acc(u2h(w.w), v, acc.w);
      }
    }

    // ---- wait barrier B_{t-1}; finalize r_{t-1}
    if (t > 0) {
      if (tid == 0) {
        while (__hip_atomic_load(ctr, __ATOMIC_RELAXED, SCOPE_AGT) < 16u * (unsigned)t)
          __builtin_amdgcn_s_sleep(1);
      }
    }
    __syncthreads();                                              // #1
    float a0 = 0.f;
    if (t > 0) {
      if (tid < 64) {
        const float* ap = P.AccP + b * 512 + tid;
#pragma unroll
        for (int k = 0; k < 8; ++k) a0 += aload(ap + k * 64);
      } else if (tid == 64) {
        const float* zp = P.ZP + b * 8;
        const float* sp = P.S2P + b * 8;
        float Z = 0.f, S2 = 0.f;
#pragma unroll
        for (int k = 0; k < 8; ++k) { Z += aload(zp + k); S2 += aload(sp + k); }
        s_scal[0] = 1.f / Z;  s_scal[1] = S2;
      }
    }
    __syncthreads();                                              // #2
    if (t > 0 && tid < 64) {
      const float iZ = s_scal[0];
      const float r = iZ * a0 + s_scal[1] * iZ * iZ * s_kprev[tid];
      s_ih[768 + tid] = (_Float16)r;
    }
    __syncthreads();                                              // #3

    // ---- GEMV part 2: rowpairs [384+q*4,+4) (r rows)
    {
      const unsigned* wp = wbase + (size_t)(384 + q * 4) * 256;
      const _Float16* ip = s_ih + 768 + q * 8;
#pragma unroll
      for (int r = 0; r < 4; ++r) {
        const uint4 w = *(const uint4*)(wp + (size_t)r * 256);
        const h2_t v = *(const h2_t*)(ip + r * 2);
        acc.x = dot2acc(u2h(w.x), v, acc.x);
        acc.y = dot2acc(u2h(w.y), v, acc.y);
        acc.z = dot2acc(u2h(w.z), v, acc.z);
        acc.w = dot2acc(u2h(w.w), v, acc.w);
      }
    }
    *(float4*)&s_part[(q << 8) + (cg << 2)] = acc;
    __syncthreads();                                              // #4

    // ---- gates reduce + LSTM -> h_t (own 64 j), publish h chunk
    if (tid < 256) {
      float g = 0.f;
#pragma unroll
      for (int k = 0; k < 8; ++k) g += s_part[(k << 8) + tid];
      s_gates[tid] = g;
    }
    __syncthreads();                                              // #5
    if (tid < 64) {
      const int jl = tid, cb = chunk * 64 + jl;
      const float gi = s_gates[jl * 4 + 0] + P.b_lstm[cb];
      const float gf = s_gates[jl * 4 + 1] + P.b_lstm[512 + cb];
      const float gg = s_gates[jl * 4 + 2] + P.b_lstm[1024 + cb];
      const float go = s_gates[jl * 4 + 3] + P.b_lstm[1536 + cb];
      const float cn = sigm(gf) * s_c[jl] + sigm(gi) * tanhf(gg);
      s_c[jl] = cn;
      const float hn = sigm(go) * tanhf(cn);
      s_h[cb] = hn;
      s_ih[256 + cb] = (_Float16)hn;
      astore(P.hbuf + b * 512 + cb, hn);
    }
    __syncthreads();                                              // #6 (drains h stores)
    if (tid == 0) __hip_atomic_fetch_add(ctr, 1u, __ATOMIC_RELEASE, SCOPE_AGT);  // post A

    // ---- shadow: apply pending rank-1 update; slot norms
    {
      const float invZp = s_scal[0];
      const float4 kp4 = ((const float4*)s_kprev)[c4];
      const int nbase = (wv * 4 + sgrp) * 8;
#pragma unroll
      for (int it = 0; it < 8; ++it) {
        float4 m4 = mreg[it];
        const float wpv = s_e[nbase + it] * invZp;   // w_{t-1}[n] (0 at t=0)
        m4.x = fmaf(wpv, kp4.x, m4.x); m4.y = fmaf(wpv, kp4.y, m4.y);
        m4.z = fmaf(wpv, kp4.z, m4.z); m4.w = fmaf(wpv, kp4.w, m4.w);
        float ssq = m4.x * m4.x + m4.y * m4.y + m4.z * m4.z + m4.w * m4.w;
#pragma unroll
        for (int off = 1; off < 16; off <<= 1) ssq += __shfl_xor(ssq, off);
        sden[it] = fmaxf(sqrtf(ssq), EPSF);
        mreg[it] = m4;
      }
    }

    // ---- wait A; fetch peers' h; prefetch x_{t+1}
    if (tid == 0) {
      while (__hip_atomic_load(ctr, __ATOMIC_RELAXED, SCOPE_AGT) < 16u * (unsigned)t + 8u)
        __builtin_amdgcn_s_sleep(1);
    }
    __syncthreads();                                              // #7
    if (tid < 448) {
      const int pc = tid >> 6;
      const int pcc = pc + (pc >= chunk ? 1 : 0);                 // peer chunks
      const int jl = tid & 63;
      const float hv = aload(P.hbuf + b * 512 + pcc * 64 + jl);
      s_h[pcc * 64 + jl] = hv;
      s_ih[256 + pcc * 64 + jl] = (_Float16)hv;
    } else if (t < 511) {
      const int i2 = tid - 448;                                   // 0..63 -> 2 rowpairs
#pragma unroll
      for (int k = 0; k < 2; ++k) {
        const int rp = i2 * 2 + k;
        const float2 xv = ((const float2*)P.xs)[((size_t)(t + 1) * 64 + b) * 128 + rp];
        h2_t hv; hv.x = (_Float16)xv.x; hv.y = (_Float16)xv.y;
        *(h2_t*)&s_ih[rp * 2] = hv;
      }
    }
    __syncthreads();                                              // #8

    // ---- local projections (fp16 weights) from complete h
    {
      {  // key|gen: 4 rowgroups x 128 cols (128 rows each)
        const int rg = tid >> 7, cl = tid & 127;
        const _Float16* wp = P.Wkg + cl;
        const float* hh = s_h + rg * 128;
        float a = 0.f;
#pragma unroll 8
        for (int r = 0; r < 128; ++r) a = fmaf(hh[r], (float)wp[(size_t)(rg * 128 + r) * 128], a);
        s_part[rg * 128 + cl] = a;
      }
      {  // y own 32-col slice: 16 rowgroups x 32 cols (32 rows each)
        const int rg = tid >> 5, c5 = tid & 31;
        const _Float16* wp = P.Wy + chunk * 32 + c5;
        const float* hh = s_h + rg * 32;
        float a = 0.f;
#pragma unroll 8
        for (int r = 0; r < 32; ++r) a = fmaf(hh[r], (float)wp[(size_t)(rg * 32 + r) * 256], a);
        s_part[1024 + (rg << 5) + c5] = a;
      }
      {  // beta partials
        float pb = s_h[tid] * P.W_beta[tid];
#pragma unroll
        for (int off = 32; off; off >>= 1) pb += __shfl_down(pb, off);
        if (lane == 0) s_bred[wv] = pb;
      }
    }
    __syncthreads();                                              // #9
    if (tid < 64) {
      float v = 0.f;
#pragma unroll
      for (int k = 0; k < 4; ++k) v += s_part[k * 128 + tid];
      s_key[tid] = v + P.b_key[tid];
    } else if (tid < 128) {
      const int c = tid - 64;
      float v = 0.f;
#pragma unroll
      for (int k = 0; k < 4; ++k) v += s_part[k * 128 + 64 + c];
      s_genv[c] = v + P.b_gen[c];
    } else if (tid < 160) {
      const int col = tid - 128, oc = chunk * 32 + col;
      float v = 0.f;
#pragma unroll
      for (int k = 0; k < 16; ++k) v += s_part[1024 + (k << 5) + col];
      P.out[((size_t)t * 64 + b) * 256 + oc] = v + P.b_out[oc];
    } else if (tid == 160) {
      float s = P.b_beta[0];
#pragma unroll
      for (int k = 0; k < 8; ++k) s += s_bred[k];
      s_scal[2] = (s > 20.f) ? s : log1pf(__expf(s));             // softplus
    }
    __syncthreads();                                              // #10
    if (wv == 0) {
      const float kv = s_key[lane];
      float sq = kv * kv;
#pragma unroll
      for (int off = 32; off; off >>= 1) sq += __shfl_down(sq, off);
      if (lane == 0) s_scal[3] = fmaxf(sqrtf(sq), EPSF);
    } else if (wv == 1 && chunk == 0) {
      const float d = s_key[lane] - s_genv[lane];
      float ds = d * d;
#pragma unroll
      for (int off = 32; off; off >>= 1) ds += __shfl_down(ds, off);
      if (lane == 0) lossacc += ds;                               // tid 64
    }
    __syncthreads();                                              // #11

    // ---- sim/exp/acc on updated register mem
    {
      const float beta = s_scal[2], kn = s_scal[3];
      const float4 kk = ((const float4*)s_key)[c4];
      float Zp = 0.f, S2p = 0.f;
      float4 acc4 = make_float4(0.f, 0.f, 0.f, 0.f);
      const int nbase = (wv * 4 + sgrp) * 8;
#pragma unroll
      for (int it = 0; it < 8; ++it) {
        const float4 m4 = mreg[it];
        float num = m4.x * kk.x + m4.y * kk.y + m4.z * kk.z + m4.w * kk.w;
#pragma unroll
        for (int off = 1; off < 16; off <<= 1) num += __shfl_xor(num, off);
        const float e = __expf(beta * (num / (sden[it] * kn)));
        if (c4 == 0) { s_e[nbase + it] = e; Zp += e; S2p += e * e; }
        acc4.x = fmaf(e, m4.x, acc4.x); acc4.y = fmaf(e, m4.y, acc4.y);
        acc4.z = fmaf(e, m4.z, acc4.z); acc4.w = fmaf(e, m4.w, acc4.w);
      }
#pragma unroll
      for (int off = 32; off; off >>= 1) { Zp += __shfl_down(Zp, off); S2p += __shfl_down(S2p, off); }
      if (lane == 0) { s_wred[wv] = Zp; s_wred[16 + wv] = S2p; }
#pragma unroll
      for (int off = 16; off < 64; off <<= 1) {
        acc4.x += __shfl_down(acc4.x, off); acc4.y += __shfl_down(acc4.y, off);
        acc4.z += __shfl_down(acc4.z, off); acc4.w += __shfl_down(acc4.w, off);
      }
      if (lane < 16) ((float4*)s_part)[wv * 16 + lane] = acc4;
    }
    __syncthreads();                                              // #12
    if (tid < 64) {
      float a = 0.f;
#pragma unroll
      for (int w = 0; w < 8; ++w) a += s_part[w * 64 + tid];
      astore(P.AccP + (b * 8 + chunk) * 64 + tid, a);
      s_kprev[tid] = s_key[tid];
    } else if (tid == 64) {
      float Z = 0.f, S2 = 0.f;
#pragma unroll
      for (int k = 0; k < 8; ++k) { Z += s_wred[k]; S2 += s_wred[16 + k]; }
      astore(P.ZP + b * 8 + chunk, Z);
      astore(P.S2P + b * 8 + chunk, S2);
    }
    __syncthreads();                                              // #13 (drains stores)
    if (tid == 0) __hip_atomic_fetch_add(ctr, 1u, __ATOMIC_RELEASE, SCOPE_AGT);  // post B
  }

  if (chunk == 0 && tid == 64) atomicAdd(P.out + 8388608, lossacc * (1.f / 4096.f));
}

//============================ prep kernels ============================
// W2h[chunk][rp][cc]: cc = jl*4+g <-> orig col g*512 + chunk*64 + jl; rows
// [0,256)=W_ih(x), [256,768)=W_hh, [768,832)=W_ih read-rows folded over R=4.
__global__ void build_w2h8(const float* __restrict__ W_ih, const float* __restrict__ W_hh,
                           unsigned* __restrict__ W2h) {
  const int id = blockIdx.x * 256 + threadIdx.x;   // over 8*416*256
  if (id >= 851968) return;
  const int chunk = id / 106496;
  const int rem   = id % 106496;
  const int rp    = rem >> 8;
  const int cc    = rem & 255;
  const int jl = cc >> 2, g = cc & 3;
  const int col = g * 512 + chunk * 64 + jl;
  float v[2];
#pragma unroll
  for (int k = 0; k < 2; ++k) {
    const int row = rp * 2 + k;
    if (row < 256)      v[k] = W_ih[(size_t)row * 2048 + col];
    else if (row < 768) v[k] = W_hh[(size_t)(row - 256) * 2048 + col];
    else {
      const float* p0 = W_ih + (size_t)(256 + (row - 768) * 4) * 2048 + col;
      v[k] = p0[0] + p0[2048] + p0[4096] + p0[6144];
    }
  }
  const __half2 h2v = __floats2half2_rn(v[0], v[1]);
  W2h[id] = *(const unsigned*)&h2v;
}

__global__ void build_wkg(const float* __restrict__ W_key, const float* __restrict__ W_gen,
                          _Float16* __restrict__ Wkg) {
  const int id = blockIdx.x * 256 + threadIdx.x;   // 512*128
  if (id >= 65536) return;
  const int row = id >> 7, cl = id & 127;
  const float v = (cl < 64) ? W_key[(size_t)row * 64 + cl] : W_gen[(size_t)row * 64 + cl - 64];
  Wkg[id] = (_Float16)v;
}

__global__ void build_wy(const float* __restrict__ W_out, _Float16* __restrict__ Wy) {
  const int id = blockIdx.x * 256 + threadIdx.x;   // 512*256
  if (id >= 131072) return;
  Wy[id] = (_Float16)W_out[id];
}

extern "C" void kernel_launch(void* const* d_in, const int* in_sizes, int n_in,
                              void* d_out, int out_size, void* d_ws, size_t ws_size,
                              hipStream_t stream) {
  const float* xs     = (const float*)d_in[0];
  const float* W_ih   = (const float*)d_in[1];
  const float* W_hh   = (const float*)d_in[2];
  const float* b_lstm = (const float*)d_in[3];
  const float* W_out  = (const float*)d_in[4];
  const float* b_out  = (const float*)d_in[5];
  const float* W_key  = (const float*)d_in[6];
  const float* b_key  = (const float*)d_in[7];
  const float* W_beta = (const float*)d_in[8];
  const float* b_beta = (const float*)d_in[9];
  const float* W_gen  = (const float*)d_in[10];
  const float* b_gen  = (const float*)d_in[11];
  float* out = (float*)d_out;

  float* ws = (float*)d_ws;
  unsigned* W2h = (unsigned*)ws;                // 851,968 u32
  _Float16* Wkg = (_Float16*)(ws + 851968);     // 65,536 h (32,768 f)
  _Float16* Wy  = (_Float16*)(ws + 884736);     // 131,072 h (65,536 f)
  float* hbuf  = ws + 950272;                   // 32,768
  float* AccP  = hbuf + 32768;                  // 32,768
  float* ZP    = AccP + 32768;                  // 512
  float* S2P   = ZP + 512;                      // 512
  unsigned* ctr = (unsigned*)(S2P + 512);       // 1,024 u32

  hipMemsetAsync(ctr, 0, 1024 * sizeof(unsigned), stream);
  hipMemsetAsync(out + 8388608, 0, sizeof(float), stream);

  build_w2h8<<<dim3(3328), dim3(256), 0, stream>>>(W_ih, W_hh, W2h);
  build_wkg<<<dim3(256),  dim3(256), 0, stream>>>(W_key, W_gen, Wkg);
  build_wy<<<dim3(512),   dim3(256), 0, stream>>>(W_out, Wy);

  P8 prm;
  prm.W2h = W2h; prm.Wkg = Wkg; prm.Wy = Wy;
  prm.b_lstm = b_lstm; prm.b_out = b_out; prm.b_key = b_key;
  prm.W_beta = W_beta; prm.b_beta = b_beta; prm.b_gen = b_gen;
  prm.xs = xs;
  prm.hbuf = hbuf; prm.AccP = AccP; prm.ZP = ZP; prm.S2P = S2P;
  prm.ctr = ctr; prm.out = out;

  // 40KB dummy dynamic LDS: total ~55KB/block -> exactly 2 blocks/CU ->
  // all 512 blocks co-resident by construction (plain launch, no coop API).
  dnc_b8<<<dim3(512), dim3(512), 40960, stream>>>(prm);
}